// Round 11
// baseline (445.490 us; speedup 1.0000x reference)
//
#include <hip/hip_runtime.h>
#include <hip/hip_bf16.h>

typedef unsigned short u16;
typedef unsigned int   u32;

// Problem constants: B=2, N=4, C=128, HEADS=8, P=4, H=W=96, TC=64, ITERS=3, HD=16
constexpr int kHW = 9216;       // 96*96
constexpr int kM  = 147456;     // 16*9216 (item-major image stride; also B*HEADS*HW items)

__device__ __forceinline__ float gelu_f(float v){ return 0.5f*v*(1.0f+erff(v*0.70710678118654752f)); }
__device__ __forceinline__ float sigm_f(float v){ return 1.0f/(1.0f+expf(-v)); }
__device__ __forceinline__ u16 f2bf(float f){
  u32 x = __float_as_uint(f);
  return (u16)((x + 0x7fffu + ((x>>16)&1u)) >> 16);   // RNE
}
__device__ __forceinline__ int nearest_n(const float* __restrict__ relt, int b){
  int nidx = 0; float bv = fabsf(relt[b*4]);
  for (int n = 1; n < 4; ++n){ float a = fabsf(relt[b*4+n]); if (a < bv){ bv=a; nidx=n; } }
  return nidx;
}

struct Bilin { int i00,i10,i01,i11; float w00,w10,w01,w11; };

__device__ __forceinline__ Bilin make_bilin(int x, int y, float ox, float oy){
  float gx = fmaf((float)x, 2.0f/95.0f, -1.0f);
  float gy = fmaf((float)y, 2.0f/95.0f, -1.0f);
  float sgx = fminf(fmaxf(gx+ox,-1.0f),1.0f);
  float sgy = fminf(fmaxf(gy+oy,-1.0f),1.0f);
  float ix = (sgx+1.0f)*0.5f*95.0f;
  float iy = (sgy+1.0f)*0.5f*95.0f;
  float x0f = floorf(ix), y0f = floorf(iy);
  float wx = ix-x0f, wy = iy-y0f;
  int x0 = min(max((int)x0f,0),95), y0 = min(max((int)y0f,0),95);
  int x1 = min(x0+1,95), y1 = min(y0+1,95);
  Bilin b;
  b.i00=(y0*96+x0)*16; b.i10=(y0*96+x1)*16; b.i01=(y1*96+x0)*16; b.i11=(y1*96+x1)*16;
  float iwx=1.0f-wx, iwy=1.0f-wy;
  b.w00=iwx*iwy; b.w10=wx*iwy; b.w01=iwx*wy; b.w11=wx*wy;
  return b;
}

__device__ __forceinline__ void sample16(const float* __restrict__ vp, const Bilin& bl, float* __restrict__ o){
  const float4* p00 = (const float4*)(vp + bl.i00);
  const float4* p10 = (const float4*)(vp + bl.i10);
  const float4* p01 = (const float4*)(vp + bl.i01);
  const float4* p11 = (const float4*)(vp + bl.i11);
  #pragma unroll
  for (int g = 0; g < 4; ++g){
    float4 a=p00[g], b=p10[g], c=p01[g], d=p11[g];
    o[g*4+0] = a.x*bl.w00 + b.x*bl.w10 + c.x*bl.w01 + d.x*bl.w11;
    o[g*4+1] = a.y*bl.w00 + b.y*bl.w10 + c.y*bl.w01 + d.y*bl.w11;
    o[g*4+2] = a.z*bl.w00 + b.z*bl.w10 + c.z*bl.w01 + d.z*bl.w11;
    o[g*4+3] = a.w*bl.w00 + b.w*bl.w10 + c.w*bl.w01 + d.w*bl.w11;
  }
}

// ---------------- transpose the five (C,C) weight matrices into [c][o] f32 ----------------
__global__ __launch_bounds__(256) void prep_k(const float* __restrict__ qw, const float* __restrict__ vw,
    const float* __restrict__ pww, const float* __restrict__ o1w, const float* __restrict__ o2w,
    float* __restrict__ wt)
{
  const float* src = (blockIdx.y==0)?qw:(blockIdx.y==1)?vw:(blockIdx.y==2)?pww:(blockIdx.y==3)?o1w:o2w;
  float* d = wt + blockIdx.y*16384;
  int i = blockIdx.x*256 + threadIdx.x;
  int o = i & 127, c = i >> 7;
  d[i] = src[o*128 + c];
}

// ---------------- MEGA-GEMM: q (y=0,1) + v (y=2..9) + pw (y=10,11) in one launch ----------
__global__ __launch_bounds__(256, 3) void gemm_qvp_k(
    const float* __restrict__ query, const float* __restrict__ values, const float* __restrict__ dwbuf,
    const float* __restrict__ wtb,
    const float* __restrict__ qb2, const float* __restrict__ vb2, const float* __restrict__ pwb2,
    float* __restrict__ qbuf, float* __restrict__ netb,
    float* __restrict__ vf32n, u16* __restrict__ vb16, const float* __restrict__ relt)
{
  __shared__ __align__(16) float a_s[16*132];
  __shared__ __align__(16) float b_s[16*132];
  const int tid = threadIdx.x;
  const int tx = tid & 15, ty = tid >> 4;
  const int iy = blockIdx.y;
  const float* inp; const float* wt; const float* bias; int img; int mode;
  if (iy < 2)       { inp = query;  wt = wtb;         bias = qb2;  img = iy;      mode = 0; }
  else if (iy < 10) { inp = values; wt = wtb + 16384; bias = vb2;  img = iy - 2;  mode = 1; }
  else              { inp = dwbuf;  wt = wtb + 32768; bias = pwb2; img = iy - 10; mode = 2; }
  const int px0 = blockIdx.x * 128;
  const int sr = tid >> 4;
  const int sc = (tid & 15) * 8;

  float acc[64];
  #pragma unroll
  for (int oj = 0; oj < 8; ++oj) {
    float bv = bias[tx*8+oj];
    #pragma unroll
    for (int pi = 0; pi < 8; ++pi) acc[pi*8+oj] = bv;
  }

  for (int kc = 0; kc < 8; ++kc) {
    const int k0 = kc*16;
    { const float4* g = (const float4*)(wt + (k0+sr)*128 + sc);
      float4 v0 = g[0], v1 = g[1];
      *(float4*)&b_s[sr*132+sc] = v0; *(float4*)&b_s[sr*132+sc+4] = v1; }
    { const float4* g = (const float4*)(inp + (size_t)(img*128 + k0 + sr)*kHW + px0 + sc);
      float4 v0 = g[0], v1 = g[1];
      *(float4*)&a_s[sr*132+sc] = v0; *(float4*)&a_s[sr*132+sc+4] = v1; }
    __syncthreads();
    #pragma unroll
    for (int k = 0; k < 16; ++k) {
      float4 b0 = *(const float4*)&b_s[k*132 + tx*8];
      float4 b1 = *(const float4*)&b_s[k*132 + tx*8 + 4];
      float4 a0 = *(const float4*)&a_s[k*132 + ty*8];
      float4 a1 = *(const float4*)&a_s[k*132 + ty*8 + 4];
      float av[8] = {a0.x,a0.y,a0.z,a0.w,a1.x,a1.y,a1.z,a1.w};
      float bv[8] = {b0.x,b0.y,b0.z,b0.w,b1.x,b1.y,b1.z,b1.w};
      #pragma unroll
      for (int pi = 0; pi < 8; ++pi)
        #pragma unroll
        for (int oj = 0; oj < 8; ++oj)
          acc[pi*8+oj] = fmaf(av[pi], bv[oj], acc[pi*8+oj]);
    }
    __syncthreads();
  }

  const int head = tx >> 1, hd0 = (tx & 1)*8;
  if (mode == 1) {
    const int b = img >> 2, n = img & 3;
    const int nidx = nearest_n(relt, b);
    #pragma unroll
    for (int pi = 0; pi < 8; ++pi) {
      const int px = px0 + ty*8 + pi;
      u16* d16 = vb16 + ((size_t)(img*8 + head)*kHW + px)*16 + hd0;
      uint4 packed;
      packed.x = (u32)f2bf(acc[pi*8+0]) | ((u32)f2bf(acc[pi*8+1])<<16);
      packed.y = (u32)f2bf(acc[pi*8+2]) | ((u32)f2bf(acc[pi*8+3])<<16);
      packed.z = (u32)f2bf(acc[pi*8+4]) | ((u32)f2bf(acc[pi*8+5])<<16);
      packed.w = (u32)f2bf(acc[pi*8+6]) | ((u32)f2bf(acc[pi*8+7])<<16);
      *(uint4*)d16 = packed;
      if (n == nidx) {           // f32 copy of nearest image (for corr + GRU sampling)
        float* dst = vf32n + ((size_t)(b*8 + head)*kHW + px)*16 + hd0;
        float4 t0 = {acc[pi*8+0],acc[pi*8+1],acc[pi*8+2],acc[pi*8+3]};
        float4 t1 = {acc[pi*8+4],acc[pi*8+5],acc[pi*8+6],acc[pi*8+7]};
        *(float4*)dst = t0; *(float4*)(dst+4) = t1;
      }
    }
  } else {
    float* outf = (mode == 0) ? qbuf : netb;
    #pragma unroll
    for (int pi = 0; pi < 8; ++pi) {
      const int px = px0 + ty*8 + pi;
      float* dst = outf + ((size_t)(img*8 + head)*kHW + px)*16 + hd0;
      float4 t0 = {acc[pi*8+0],acc[pi*8+1],acc[pi*8+2],acc[pi*8+3]};
      float4 t1 = {acc[pi*8+4],acc[pi*8+5],acc[pi*8+6],acc[pi*8+7]};
      *(float4*)dst = t0; *(float4*)(dst+4) = t1;
    }
  }
}

// ---------------- fused o1(gelu) -> o2(gate), 64-px tiles (288 blocks, ~3 blocks/CU) -------
__global__ __launch_bounds__(256) void o1o2_k(const u16* __restrict__ oat,
    const float* __restrict__ wt1, const float* __restrict__ o1b,
    const float* __restrict__ wt2, const float* __restrict__ o2b,
    const float* __restrict__ gate, float* __restrict__ out)
{
  __shared__ __align__(16) float a_s[16*68];
  __shared__ __align__(16) float b_s[16*132];
  __shared__ __align__(16) float mid[128*68];   // 34.8 KB
  const int tid = threadIdx.x;
  const int tx = tid & 15, ty = tid >> 4;       // tx: 8-out group, ty: 4-px group
  const int img = blockIdx.y;
  const int px0 = blockIdx.x * 64;
  const int sr = tid >> 4;
  const int sc = (tid & 15) * 8;

  float acc[32];                                 // [pi(4)][oj(8)]
  // ---- stage 1: o1 GEMM (bf16 item-major input), bias-first k-ascending ----
  #pragma unroll
  for (int oj = 0; oj < 8; ++oj) {
    float bv = o1b[tx*8+oj];
    #pragma unroll
    for (int pi = 0; pi < 4; ++pi) acc[pi*8+oj] = bv;
  }
  for (int kc = 0; kc < 8; ++kc) {
    const int k0 = kc*16;
    { const float4* g = (const float4*)(wt1 + (k0+sr)*128 + sc);
      float4 v0 = g[0], v1 = g[1];
      *(float4*)&b_s[sr*132+sc] = v0; *(float4*)&b_s[sr*132+sc+4] = v1; }
    { const int px = tid & 63, hd0 = (tid >> 6) * 4;
      uint2 raw = *(const uint2*)(oat + ((size_t)(img*8 + kc)*kHW + px0 + px)*16 + hd0);
      a_s[(hd0+0)*68+px] = __uint_as_float(raw.x<<16);
      a_s[(hd0+1)*68+px] = __uint_as_float(raw.x&0xffff0000u);
      a_s[(hd0+2)*68+px] = __uint_as_float(raw.y<<16);
      a_s[(hd0+3)*68+px] = __uint_as_float(raw.y&0xffff0000u); }
    __syncthreads();
    #pragma unroll
    for (int k = 0; k < 16; ++k) {
      float4 b0 = *(const float4*)&b_s[k*132 + tx*8];
      float4 b1 = *(const float4*)&b_s[k*132 + tx*8 + 4];
      float4 a0 = *(const float4*)&a_s[k*68 + ty*4];
      float av[4] = {a0.x,a0.y,a0.z,a0.w};
      float bv[8] = {b0.x,b0.y,b0.z,b0.w,b1.x,b1.y,b1.z,b1.w};
      #pragma unroll
      for (int pi = 0; pi < 4; ++pi)
        #pragma unroll
        for (int oj = 0; oj < 8; ++oj)
          acc[pi*8+oj] = fmaf(av[pi], bv[oj], acc[pi*8+oj]);
    }
    __syncthreads();
  }
  // gelu -> mid (planar [ch][px_local])
  #pragma unroll
  for (int oj = 0; oj < 8; ++oj)
    #pragma unroll
    for (int pi = 0; pi < 4; ++pi)
      mid[(tx*8+oj)*68 + ty*4+pi] = gelu_f(acc[pi*8+oj]);
  __syncthreads();

  // ---- stage 2: o2 GEMM, A read directly from LDS mid ----
  #pragma unroll
  for (int oj = 0; oj < 8; ++oj) {
    float bv = o2b[tx*8+oj];
    #pragma unroll
    for (int pi = 0; pi < 4; ++pi) acc[pi*8+oj] = bv;
  }
  for (int kc = 0; kc < 8; ++kc) {
    const int k0 = kc*16;
    { const float4* g = (const float4*)(wt2 + (k0+sr)*128 + sc);
      float4 v0 = g[0], v1 = g[1];
      *(float4*)&b_s[sr*132+sc] = v0; *(float4*)&b_s[sr*132+sc+4] = v1; }
    __syncthreads();
    #pragma unroll
    for (int k = 0; k < 16; ++k) {
      float4 b0 = *(const float4*)&b_s[k*132 + tx*8];
      float4 b1 = *(const float4*)&b_s[k*132 + tx*8 + 4];
      float4 a0 = *(const float4*)&mid[(k0+k)*68 + ty*4];
      float av[4] = {a0.x,a0.y,a0.z,a0.w};
      float bv[8] = {b0.x,b0.y,b0.z,b0.w,b1.x,b1.y,b1.z,b1.w};
      #pragma unroll
      for (int pi = 0; pi < 4; ++pi)
        #pragma unroll
        for (int oj = 0; oj < 8; ++oj)
          acc[pi*8+oj] = fmaf(av[pi], bv[oj], acc[pi*8+oj]);
    }
    __syncthreads();
  }
  #pragma unroll
  for (int oj = 0; oj < 8; ++oj) {
    const int o = tx*8 + oj;
    float* dst = out + (size_t)(img*128 + o)*kHW + px0 + ty*4;
    float sg = sigm_f(gate[o]);
    float4 t0 = {acc[0*8+oj]*sg, acc[1*8+oj]*sg, acc[2*8+oj]*sg, acc[3*8+oj]*sg};
    *(float4*)dst = t0;
  }
}

// ---------------- depthwise 7x7 + bias + exact gelu ----------------
__global__ __launch_bounds__(256) void dw_k(const float* __restrict__ q, const float* __restrict__ dww,
    const float* __restrict__ dwb, float* __restrict__ outf)
{
  int idx = blockIdx.x*256 + threadIdx.x;
  int px = idx % kHW;
  int bc = idx / kHW;
  int c = bc & 127;
  int x = px % 96, y = px / 96;
  float s = dwb[c];
  const float* qb = q + (size_t)bc*kHW;
  #pragma unroll
  for (int ky = 0; ky < 7; ++ky) {
    int yy = y + ky - 3;
    if (yy < 0 || yy > 95) continue;
    #pragma unroll
    for (int kx = 0; kx < 7; ++kx) {
      int xx = x + kx - 3;
      if (xx < 0 || xx > 95) continue;
      s = fmaf(qb[yy*96+xx], dww[c*49 + ky*7 + kx], s);
    }
  }
  outf[idx] = gelu_f(s);
}

// ---------------- time bias: (B,HEADS,N) ----------------
__global__ void tb_k(const float* __restrict__ te, const float* __restrict__ tw,
                     const float* __restrict__ tbias, float* __restrict__ tbb)
{
  int i = threadIdx.x;
  if (i >= 64) return;
  int b = i >> 5, h = (i >> 2) & 7, n = i & 3;
  float s = tbias[h];
  for (int tc = 0; tc < 64; ++tc) s = fmaf(te[(b*4+n)*64 + tc], tw[h*64+tc], s);
  tbb[(b*8+h)*4 + n] = s;
}

// ---------------- FUSED v6: r9 structure, weights via uniform scalar loads (no LDS) --------
// All weight indices are lane-invariant -> compiler emits s_load via scalar K$ pipe,
// freeing the LDS/vector-mem pipe that was ~1300 ds_read_b128/wave in r10.
__global__ __launch_bounds__(256) void fused_k(
    const float* __restrict__ qb, const float* __restrict__ vf32, const u16* __restrict__ vb16,
    const float* __restrict__ netb, const float* __restrict__ relt,
    const float* __restrict__ wih, const float* __restrict__ whh,
    const float* __restrict__ bihp, const float* __restrict__ bhhp,
    const float* __restrict__ offw, const float* __restrict__ offbp,
    const float* __restrict__ aw, const float* __restrict__ abp,
    const float* __restrict__ tbb,
    u16* __restrict__ outattn16, float* __restrict__ entb)
{
  const int tid = threadIdx.x;
  // XCD swizzle (r5-validated): 576 blocks = 8 XCDs x 72
  const int vblk = (blockIdx.x & 7)*72 + (blockIdx.x >> 3);
  const int item = vblk*256 + tid;
  const int yx = item % kHW; const int bh = item / kHW;
  const int b = bh >> 3, head = bh & 7;
  const int x = yx % 96, y = yx / 96;
  const float* vp = vf32 + (size_t)(b*8 + head)*kM;   // nearest-n image, f32

  // ---- correlation argmax (f64, all 5 taps' loads hoisted via clamped addresses) ----
  float off_[8], attn_[4];
  {
    float qv[16];
    { const float4* q4 = (const float4*)(qb + (size_t)bh*kM + yx*16);
      #pragma unroll
      for (int g = 0; g < 4; ++g){ float4 t = q4[g]; qv[g*4]=t.x; qv[g*4+1]=t.y; qv[g*4+2]=t.z; qv[g*4+3]=t.w; } }
    const int sdx[5] = {0,-1,1,0,0};   // SHIFTS entries are (dx,dy)
    const int sdy[5] = {0,0,0,-1,1};
    float4 tv[5][4]; bool valid[5];
    #pragma unroll
    for (int s5 = 0; s5 < 5; ++s5) {
      int sy = y - sdy[s5], sx = x - sdx[s5];
      valid[s5] = (sy >= 0 && sy < 96 && sx >= 0 && sx < 96);
      int syc = min(max(sy,0),95), sxc = min(max(sx,0),95);
      const float4* tp = (const float4*)(vp + (syc*96+sxc)*16);
      tv[s5][0] = tp[0]; tv[s5][1] = tp[1]; tv[s5][2] = tp[2]; tv[s5][3] = tp[3];
    }
    double bsc = 0.0; int best = 0;
    #pragma unroll
    for (int s5 = 0; s5 < 5; ++s5) {
      double sc = 0.0;
      if (valid[s5]) {
        const float* tp = (const float*)&tv[s5][0];
        #pragma unroll
        for (int hd = 0; hd < 16; ++hd) sc += (double)qv[hd]*(double)tp[hd];
      }
      if (s5 == 0) { bsc = sc; best = 0; }
      else if (sc > bsc) { bsc = sc; best = s5; }
    }
    const float STEP = 2.0f/96.0f;
    float ox = 0.f, oy = 0.f;        // reference swap: x-offset = dy*2/W, y-offset = dx*2/H
    if (best == 3) ox = -STEP; else if (best == 4) ox = STEP;
    if (best == 1) oy = -STEP; else if (best == 2) oy = STEP;
    #pragma unroll
    for (int p = 0; p < 4; ++p) { off_[2*p] = ox; off_[2*p+1] = oy; attn_[p] = 0.0f; }
  }

  float h[16];
  { const float4* n4 = (const float4*)(netb + (size_t)item*16);
    #pragma unroll
    for (int g = 0; g < 4; ++g){ float4 t = n4[g]; h[g*4]=t.x; h[g*4+1]=t.y; h[g*4+2]=t.z; h[g*4+3]=t.w; } }

  // ---- 3 GRU refinement iterations, all state in registers (f32 sampling) ----
  for (int it = 0; it < 3; ++it) {
    const float p0x = off_[0];
    const float p0y = off_[1];
    Bilin bl = make_bilin(x, y, p0x, p0y);
    float xv[18];
    sample16(vp, bl, xv);
    xv[16] = p0x; xv[17] = p0y;

    float hn[16];
    #pragma unroll 2
    for (int j = 0; j < 16; ++j) {
      // independent accumulator chains; each keeps bias-first, k-ascending order (bitwise = r10;
      // the two dropped pad terms were exact no-ops fmaf(x,0,s))
      float g0 = bihp[j], g1 = bihp[16+j], g2 = bihp[32+j];
      const float* w0 = wih + j*18;
      const float* w1 = wih + (16+j)*18;
      const float* w2 = wih + (32+j)*18;
      #pragma unroll
      for (int k = 0; k < 18; ++k) {
        float a = xv[k];
        g0 = fmaf(a, w0[k], g0);
        g1 = fmaf(a, w1[k], g1);
        g2 = fmaf(a, w2[k], g2);
      }
      float t0 = bhhp[j], t1 = bhhp[16+j], t2 = bhhp[32+j];
      const float* v0 = whh + j*16;
      const float* v1 = whh + (16+j)*16;
      const float* v2 = whh + (32+j)*16;
      #pragma unroll
      for (int k = 0; k < 16; ++k) {
        float a = h[k];
        t0 = fmaf(a, v0[k], t0);
        t1 = fmaf(a, v1[k], t1);
        t2 = fmaf(a, v2[k], t2);
      }
      float r = sigm_f(g0 + t0);
      float z = sigm_f(g1 + t1);
      float nn = tanhf(fmaf(r, t2, g2));
      hn[j] = fmaf(z, h[j], (1.0f - z)*nn);
    }
    #pragma unroll
    for (int j = 0; j < 16; ++j) h[j] = hn[j];

    #pragma unroll
    for (int d = 0; d < 8; ++d) {
      const float* wr = offw + d*16;
      float s = offbp[d];
      #pragma unroll
      for (int k = 0; k < 16; ++k) s = fmaf(h[k], wr[k], s);
      off_[d] += s;
    }
    #pragma unroll
    for (int p = 0; p < 4; ++p) {
      const float* wr = aw + p*16;
      float s = abp[p];
      #pragma unroll
      for (int k = 0; k < 16; ++k) s = fmaf(h[k], wr[k], s);
      attn_[p] += s;
    }
  }

  // ---- softmax over (N,P) + entropy ----
  float lg[16];
  #pragma unroll
  for (int n = 0; n < 4; ++n) {
    float tv2 = tbb[(b*8+head)*4 + n];
    #pragma unroll
    for (int p = 0; p < 4; ++p) lg[n*4+p] = attn_[p] + tv2;
  }
  float mx = lg[0];
  #pragma unroll
  for (int i = 1; i < 16; ++i) mx = fmaxf(mx, lg[i]);
  float es = 0.f;
  #pragma unroll
  for (int i = 0; i < 16; ++i){ lg[i] = expf(lg[i]-mx); es += lg[i]; }
  float inv = 1.0f/es;
  float ent = 0.f;
  #pragma unroll
  for (int i = 0; i < 16; ++i){ lg[i] *= inv; ent -= lg[i]*logf(lg[i] + 1e-8f); }
  entb[item] = ent;

  // ---- N*P deformable sampling (bf16 v), p-outer n-inner, loads batched per p ----
  float acc[16];
  #pragma unroll
  for (int j = 0; j < 16; ++j) acc[j] = 0.f;
  #pragma unroll
  for (int p = 0; p < 4; ++p) {
    Bilin bl = make_bilin(x, y, off_[2*p], off_[2*p+1]);
    uint4 raw[4][8];
    #pragma unroll
    for (int n = 0; n < 4; ++n) {
      const u16* vpn = vb16 + (size_t)((b*4+n)*8 + head)*kM;
      raw[n][0] = *(const uint4*)(vpn + bl.i00); raw[n][1] = *(const uint4*)(vpn + bl.i00 + 8);
      raw[n][2] = *(const uint4*)(vpn + bl.i10); raw[n][3] = *(const uint4*)(vpn + bl.i10 + 8);
      raw[n][4] = *(const uint4*)(vpn + bl.i01); raw[n][5] = *(const uint4*)(vpn + bl.i01 + 8);
      raw[n][6] = *(const uint4*)(vpn + bl.i11); raw[n][7] = *(const uint4*)(vpn + bl.i11 + 8);
    }
    #pragma unroll
    for (int n = 0; n < 4; ++n) {
      u32 aw2[8] = {raw[n][0].x,raw[n][0].y,raw[n][0].z,raw[n][0].w, raw[n][1].x,raw[n][1].y,raw[n][1].z,raw[n][1].w};
      u32 bw2[8] = {raw[n][2].x,raw[n][2].y,raw[n][2].z,raw[n][2].w, raw[n][3].x,raw[n][3].y,raw[n][3].z,raw[n][3].w};
      u32 cw2[8] = {raw[n][4].x,raw[n][4].y,raw[n][4].z,raw[n][4].w, raw[n][5].x,raw[n][5].y,raw[n][5].z,raw[n][5].w};
      u32 dw2[8] = {raw[n][6].x,raw[n][6].y,raw[n][6].z,raw[n][6].w, raw[n][7].x,raw[n][7].y,raw[n][7].z,raw[n][7].w};
      float wnp = lg[n*4+p];
      #pragma unroll
      for (int g = 0; g < 8; ++g){
        float alo = __uint_as_float(aw2[g]<<16), ahi = __uint_as_float(aw2[g]&0xffff0000u);
        float blo = __uint_as_float(bw2[g]<<16), bhi = __uint_as_float(bw2[g]&0xffff0000u);
        float clo = __uint_as_float(cw2[g]<<16), chi = __uint_as_float(cw2[g]&0xffff0000u);
        float dlo = __uint_as_float(dw2[g]<<16), dhi = __uint_as_float(dw2[g]&0xffff0000u);
        float s0 = alo*bl.w00 + blo*bl.w10 + clo*bl.w01 + dlo*bl.w11;
        float s1 = ahi*bl.w00 + bhi*bl.w10 + chi*bl.w01 + dhi*bl.w11;
        acc[g*2+0] = fmaf(wnp, s0, acc[g*2+0]);
        acc[g*2+1] = fmaf(wnp, s1, acc[g*2+1]);
      }
    }
  }
  uint4 pk0, pk1;
  pk0.x = (u32)f2bf(acc[0])  | ((u32)f2bf(acc[1])<<16);
  pk0.y = (u32)f2bf(acc[2])  | ((u32)f2bf(acc[3])<<16);
  pk0.z = (u32)f2bf(acc[4])  | ((u32)f2bf(acc[5])<<16);
  pk0.w = (u32)f2bf(acc[6])  | ((u32)f2bf(acc[7])<<16);
  pk1.x = (u32)f2bf(acc[8])  | ((u32)f2bf(acc[9])<<16);
  pk1.y = (u32)f2bf(acc[10]) | ((u32)f2bf(acc[11])<<16);
  pk1.z = (u32)f2bf(acc[12]) | ((u32)f2bf(acc[13])<<16);
  pk1.w = (u32)f2bf(acc[14]) | ((u32)f2bf(acc[15])<<16);
  *(uint4*)(outattn16 + (size_t)item*16)     = pk0;
  *(uint4*)(outattn16 + (size_t)item*16 + 8) = pk1;
}

// ---------------- entropy mean over heads -> confidence/entropy outputs (f32) ----------------
__global__ __launch_bounds__(256) void ent_k(const float* __restrict__ entb, float* __restrict__ outf)
{
  int idx = blockIdx.x*256 + threadIdx.x;   // B*HW = 18432
  int b = idx / kHW, yx = idx % kHW;
  float s = 0.f;
  #pragma unroll
  for (int h8 = 0; h8 < 8; ++h8) s += entb[(b*8+h8)*kHW + yx];
  s *= 0.125f;
  float conf = 1.0f - fminf(fmaxf(s / (2.772588722239781f + 1e-8f), 0.0f), 1.0f);
  outf[2359296 + idx]         = conf;
  outf[2359296 + 18432 + idx] = s;
}

extern "C" void kernel_launch(void* const* d_in, const int* in_sizes, int n_in,
                              void* d_out, int out_size, void* d_ws, size_t ws_size,
                              hipStream_t stream)
{
  const float* query  = (const float*)d_in[0];
  const float* values = (const float*)d_in[1];
  const float* relt   = (const float*)d_in[2];
  const float* time_enc = (const float*)d_in[3];
  const float* qw  = (const float*)d_in[4];
  const float* qb  = (const float*)d_in[5];
  const float* vw  = (const float*)d_in[6];
  const float* vb  = (const float*)d_in[7];
  const float* dww = (const float*)d_in[8];
  const float* dwb = (const float*)d_in[9];
  const float* pww = (const float*)d_in[10];
  const float* pwb = (const float*)d_in[11];
  const float* wih = (const float*)d_in[12];
  const float* whh = (const float*)d_in[13];
  const float* bih = (const float*)d_in[14];
  const float* bhh = (const float*)d_in[15];
  const float* offw = (const float*)d_in[16];
  const float* offb = (const float*)d_in[17];
  const float* aw  = (const float*)d_in[18];
  const float* ab  = (const float*)d_in[19];
  const float* tw  = (const float*)d_in[20];
  const float* tb  = (const float*)d_in[21];
  const float* o1w = (const float*)d_in[22];
  const float* o1b = (const float*)d_in[23];
  const float* o2w = (const float*)d_in[24];
  const float* o2b = (const float*)d_in[25];
  const float* gate = (const float*)d_in[26];
  float* out = (float*)d_out;
  float* ws = (float*)d_ws;

  // workspace layout (f32 slots) — total 14385280 slots = 57.5 MB
  u16*   vb16   = (u16*)ws;                        // bf16 v, item-major [(b,n,h)][yx][16] : 4718592 fl
  float* vf32n  = ws + 4718592;                    // f32 v of nearest n [(b,h)][yx][16]   : 2359296
  float* qbuf   = ws + 7077888;                    // q item-major [(b,h)][yx][16]          : 2359296
  float* netb   = ws + 9437184;                    // net item-major [bh][yx][16]           : 2359296
  float* dwbuf  = ws + 11796480;                   // dw mid planar [b][c][yx]              : 2359296 ; reused as outattn16
  u16*   oat16  = (u16*)dwbuf;                     // outattn bf16 [item][16]               : 2359296 u16
  float* entbf  = ws + 14155776;                   // per-head entropy                      :  147456
  float* tbbuf  = ws + 14303232;                   // time bias                             :      64
  float* wtbuf  = ws + 14303360;                   // 5 transposed weights                  :   81920
  if (ws_size < 14385280ull * 4ull) return;

  float* wt_o1 = wtbuf + 49152;
  float* wt_o2 = wtbuf + 65536;

  dim3 blk(256,1,1);
  // 0. transpose weights
  prep_k<<<dim3(64,5,1), blk, 0, stream>>>(qw, vw, pww, o1w, o2w, wtbuf);
  // 1. depthwise 7x7 + gelu -> planar dwbuf
  dw_k<<<dim3(9216,1,1), blk, 0, stream>>>(query, dww, dwb, dwbuf);
  // 2. MEGA-GEMM: q + v + pw in one launch (864 blocks)
  gemm_qvp_k<<<dim3(72,12,1), blk, 0, stream>>>(query, values, dwbuf, wtbuf,
                                                qb, vb, pwb, qbuf, netb, vf32n, vb16, relt);
  // 3. time bias
  tb_k<<<dim3(1,1,1), dim3(64,1,1), 0, stream>>>(time_enc, tw, tb, tbbuf);
  // 4. FUSED v6 (scalar-load weights) -> oat16 (overwrites dwbuf, its consumers are done)
  fused_k<<<dim3(576,1,1), blk, 0, stream>>>(qbuf, vf32n, vb16, netb, relt,
                                             wih, whh, bih, bhh, offw, offb, aw, ab,
                                             tbbuf, oat16, entbf);
  // 5. entropy mean / confidence -> d_out tail (f32)
  ent_k<<<dim3(72,1,1), blk, 0, stream>>>(entbf, out);
  // 6. fused o1(gelu)->o2(gate), mid in LDS, 64-px tiles -> f32 d_out
  o1o2_k<<<dim3(144,2,1), blk, 0, stream>>>(oat16, wt_o1, o1b, wt_o2, o2b, gate, out);
}

// Round 12
// 423.644 us; speedup vs baseline: 1.0516x; 1.0516x over previous
//
#include <hip/hip_runtime.h>
#include <hip/hip_bf16.h>

typedef unsigned short u16;
typedef unsigned int   u32;

// Problem constants: B=2, N=4, C=128, HEADS=8, P=4, H=W=96, TC=64, ITERS=3, HD=16
constexpr int kHW = 9216;       // 96*96
constexpr int kM  = 147456;     // 16*9216 (item-major image stride; also B*HEADS*HW items)

__device__ __forceinline__ float gelu_f(float v){ return 0.5f*v*(1.0f+erff(v*0.70710678118654752f)); }
__device__ __forceinline__ float sigm_f(float v){ return 1.0f/(1.0f+expf(-v)); }
__device__ __forceinline__ u16 f2bf(float f){
  u32 x = __float_as_uint(f);
  return (u16)((x + 0x7fffu + ((x>>16)&1u)) >> 16);   // RNE
}
__device__ __forceinline__ int nearest_n(const float* __restrict__ relt, int b){
  int nidx = 0; float bv = fabsf(relt[b*4]);
  for (int n = 1; n < 4; ++n){ float a = fabsf(relt[b*4+n]); if (a < bv){ bv=a; nidx=n; } }
  return nidx;
}

struct Bilin { int i00,i10,i01,i11; float w00,w10,w01,w11; };

__device__ __forceinline__ Bilin make_bilin(int x, int y, float ox, float oy){
  float gx = fmaf((float)x, 2.0f/95.0f, -1.0f);
  float gy = fmaf((float)y, 2.0f/95.0f, -1.0f);
  float sgx = fminf(fmaxf(gx+ox,-1.0f),1.0f);
  float sgy = fminf(fmaxf(gy+oy,-1.0f),1.0f);
  float ix = (sgx+1.0f)*0.5f*95.0f;
  float iy = (sgy+1.0f)*0.5f*95.0f;
  float x0f = floorf(ix), y0f = floorf(iy);
  float wx = ix-x0f, wy = iy-y0f;
  int x0 = min(max((int)x0f,0),95), y0 = min(max((int)y0f,0),95);
  int x1 = min(x0+1,95), y1 = min(y0+1,95);
  Bilin b;
  b.i00=(y0*96+x0)*16; b.i10=(y0*96+x1)*16; b.i01=(y1*96+x0)*16; b.i11=(y1*96+x1)*16;
  float iwx=1.0f-wx, iwy=1.0f-wy;
  b.w00=iwx*iwy; b.w10=wx*iwy; b.w01=iwx*wy; b.w11=wx*wy;
  return b;
}

__device__ __forceinline__ void sample16(const float* __restrict__ vp, const Bilin& bl, float* __restrict__ o){
  const float4* p00 = (const float4*)(vp + bl.i00);
  const float4* p10 = (const float4*)(vp + bl.i10);
  const float4* p01 = (const float4*)(vp + bl.i01);
  const float4* p11 = (const float4*)(vp + bl.i11);
  #pragma unroll
  for (int g = 0; g < 4; ++g){
    float4 a=p00[g], b=p10[g], c=p01[g], d=p11[g];
    o[g*4+0] = a.x*bl.w00 + b.x*bl.w10 + c.x*bl.w01 + d.x*bl.w11;
    o[g*4+1] = a.y*bl.w00 + b.y*bl.w10 + c.y*bl.w01 + d.y*bl.w11;
    o[g*4+2] = a.z*bl.w00 + b.z*bl.w10 + c.z*bl.w01 + d.z*bl.w11;
    o[g*4+3] = a.w*bl.w00 + b.w*bl.w10 + c.w*bl.w01 + d.w*bl.w11;
  }
}

// ---------------- PRE: dw conv (blocks 0..9215) + weight transpose (9216..9535) + tb (9536) --
// The three jobs are mutually independent (no intra-launch ordering assumed).
__global__ __launch_bounds__(256) void pre_k(
    const float* __restrict__ query, const float* __restrict__ dww, const float* __restrict__ dwb,
    float* __restrict__ dwbuf,
    const float* __restrict__ qw, const float* __restrict__ vw, const float* __restrict__ pww,
    const float* __restrict__ o1w, const float* __restrict__ o2w, float* __restrict__ wt,
    const float* __restrict__ te, const float* __restrict__ tw, const float* __restrict__ tbias,
    float* __restrict__ tbb)
{
  const int bid = blockIdx.x;
  const int tid = threadIdx.x;
  if (bid < 9216) {
    // depthwise 7x7 + bias + exact gelu (identical math to r10 dw_k)
    int idx = bid*256 + tid;
    int px = idx % kHW;
    int bc = idx / kHW;
    int c = bc & 127;
    int x = px % 96, y = px / 96;
    float s = dwb[c];
    const float* qb = query + (size_t)bc*kHW;
    #pragma unroll
    for (int ky = 0; ky < 7; ++ky) {
      int yy = y + ky - 3;
      if (yy < 0 || yy > 95) continue;
      #pragma unroll
      for (int kx = 0; kx < 7; ++kx) {
        int xx = x + kx - 3;
        if (xx < 0 || xx > 95) continue;
        s = fmaf(qb[yy*96+xx], dww[c*49 + ky*7 + kx], s);
      }
    }
    dwbuf[idx] = gelu_f(s);
  } else if (bid < 9536) {
    // transpose 5 weight matrices into [c][o]
    int i = (bid - 9216)*256 + tid;            // 0..81919
    int m = i >> 14, r = i & 16383;
    const float* src = (m==0)?qw:(m==1)?vw:(m==2)?pww:(m==3)?o1w:o2w;
    int o = r & 127, c = r >> 7;
    wt[m*16384 + r] = src[o*128 + c];
  } else {
    // time bias
    if (tid >= 64) return;
    int b = tid >> 5, h = (tid >> 2) & 7, n = tid & 3;
    float s = tbias[h];
    for (int tc = 0; tc < 64; ++tc) s = fmaf(te[(b*4+n)*64 + tc], tw[h*64+tc], s);
    tbb[(b*8+h)*4 + n] = s;
  }
}

// ---------------- MEGA-GEMM: q (y=0,1) + v (y=2..9) + pw (y=10,11) in one launch ----------
__global__ __launch_bounds__(256, 3) void gemm_qvp_k(
    const float* __restrict__ query, const float* __restrict__ values, const float* __restrict__ dwbuf,
    const float* __restrict__ wtb,
    const float* __restrict__ qb2, const float* __restrict__ vb2, const float* __restrict__ pwb2,
    float* __restrict__ qbuf, float* __restrict__ netb,
    float* __restrict__ vf32n, u16* __restrict__ vb16, const float* __restrict__ relt)
{
  __shared__ __align__(16) float a_s[16*132];
  __shared__ __align__(16) float b_s[16*132];
  const int tid = threadIdx.x;
  const int tx = tid & 15, ty = tid >> 4;
  const int iy = blockIdx.y;
  const float* inp; const float* wt; const float* bias; int img; int mode;
  if (iy < 2)       { inp = query;  wt = wtb;         bias = qb2;  img = iy;      mode = 0; }
  else if (iy < 10) { inp = values; wt = wtb + 16384; bias = vb2;  img = iy - 2;  mode = 1; }
  else              { inp = dwbuf;  wt = wtb + 32768; bias = pwb2; img = iy - 10; mode = 2; }
  const int px0 = blockIdx.x * 128;
  const int sr = tid >> 4;
  const int sc = (tid & 15) * 8;

  float acc[64];
  #pragma unroll
  for (int oj = 0; oj < 8; ++oj) {
    float bv = bias[tx*8+oj];
    #pragma unroll
    for (int pi = 0; pi < 8; ++pi) acc[pi*8+oj] = bv;
  }

  for (int kc = 0; kc < 8; ++kc) {
    const int k0 = kc*16;
    { const float4* g = (const float4*)(wt + (k0+sr)*128 + sc);
      float4 v0 = g[0], v1 = g[1];
      *(float4*)&b_s[sr*132+sc] = v0; *(float4*)&b_s[sr*132+sc+4] = v1; }
    { const float4* g = (const float4*)(inp + (size_t)(img*128 + k0 + sr)*kHW + px0 + sc);
      float4 v0 = g[0], v1 = g[1];
      *(float4*)&a_s[sr*132+sc] = v0; *(float4*)&a_s[sr*132+sc+4] = v1; }
    __syncthreads();
    #pragma unroll
    for (int k = 0; k < 16; ++k) {
      float4 b0 = *(const float4*)&b_s[k*132 + tx*8];
      float4 b1 = *(const float4*)&b_s[k*132 + tx*8 + 4];
      float4 a0 = *(const float4*)&a_s[k*132 + ty*8];
      float4 a1 = *(const float4*)&a_s[k*132 + ty*8 + 4];
      float av[8] = {a0.x,a0.y,a0.z,a0.w,a1.x,a1.y,a1.z,a1.w};
      float bv[8] = {b0.x,b0.y,b0.z,b0.w,b1.x,b1.y,b1.z,b1.w};
      #pragma unroll
      for (int pi = 0; pi < 8; ++pi)
        #pragma unroll
        for (int oj = 0; oj < 8; ++oj)
          acc[pi*8+oj] = fmaf(av[pi], bv[oj], acc[pi*8+oj]);
    }
    __syncthreads();
  }

  const int head = tx >> 1, hd0 = (tx & 1)*8;
  if (mode == 1) {
    const int b = img >> 2, n = img & 3;
    const int nidx = nearest_n(relt, b);
    #pragma unroll
    for (int pi = 0; pi < 8; ++pi) {
      const int px = px0 + ty*8 + pi;
      u16* d16 = vb16 + ((size_t)(img*8 + head)*kHW + px)*16 + hd0;
      uint4 packed;
      packed.x = (u32)f2bf(acc[pi*8+0]) | ((u32)f2bf(acc[pi*8+1])<<16);
      packed.y = (u32)f2bf(acc[pi*8+2]) | ((u32)f2bf(acc[pi*8+3])<<16);
      packed.z = (u32)f2bf(acc[pi*8+4]) | ((u32)f2bf(acc[pi*8+5])<<16);
      packed.w = (u32)f2bf(acc[pi*8+6]) | ((u32)f2bf(acc[pi*8+7])<<16);
      *(uint4*)d16 = packed;
      if (n == nidx) {           // f32 copy of nearest image (for corr + GRU sampling)
        float* dst = vf32n + ((size_t)(b*8 + head)*kHW + px)*16 + hd0;
        float4 t0 = {acc[pi*8+0],acc[pi*8+1],acc[pi*8+2],acc[pi*8+3]};
        float4 t1 = {acc[pi*8+4],acc[pi*8+5],acc[pi*8+6],acc[pi*8+7]};
        *(float4*)dst = t0; *(float4*)(dst+4) = t1;
      }
    }
  } else {
    float* outf = (mode == 0) ? qbuf : netb;
    #pragma unroll
    for (int pi = 0; pi < 8; ++pi) {
      const int px = px0 + ty*8 + pi;
      float* dst = outf + ((size_t)(img*8 + head)*kHW + px)*16 + hd0;
      float4 t0 = {acc[pi*8+0],acc[pi*8+1],acc[pi*8+2],acc[pi*8+3]};
      float4 t1 = {acc[pi*8+4],acc[pi*8+5],acc[pi*8+6],acc[pi*8+7]};
      *(float4*)dst = t0; *(float4*)(dst+4) = t1;
    }
  }
}

// ---------------- FUSED (r10 version, reverted): LDS weights + hoisted loads ----------------
__global__ __launch_bounds__(256) void fused_k(
    const float* __restrict__ qb, const float* __restrict__ vf32, const u16* __restrict__ vb16,
    const float* __restrict__ netb, const float* __restrict__ relt,
    const float* __restrict__ wih, const float* __restrict__ whh,
    const float* __restrict__ bihp, const float* __restrict__ bhhp,
    const float* __restrict__ offw, const float* __restrict__ offbp,
    const float* __restrict__ aw, const float* __restrict__ abp,
    const float* __restrict__ tbb,
    u16* __restrict__ outattn16, float* __restrict__ entb)
{
  __shared__ __align__(16) float s_wih[48*20];   // rows padded 18->20 (pad=0)
  __shared__ __align__(16) float s_whh[48*16];
  __shared__ __align__(16) float s_offw[8*16];
  __shared__ __align__(16) float s_aw[4*16];
  __shared__ float s_bih[48], s_bhh[48], s_offb[8], s_ab[4];
  const int tid = threadIdx.x;
  for (int i = tid; i < 960; i += 256){ int g = i/20, k = i%20; s_wih[i] = (k<18)? wih[g*18+k] : 0.0f; }
  for (int i = tid; i < 768; i += 256) s_whh[i] = whh[i];
  if (tid < 128) s_offw[tid] = offw[tid];
  if (tid < 64)  s_aw[tid]  = aw[tid];
  if (tid < 48){ s_bih[tid] = bihp[tid]; s_bhh[tid] = bhhp[tid]; }
  if (tid < 8)   s_offb[tid] = offbp[tid];
  if (tid < 4)   s_ab[tid]  = abp[tid];

  // XCD swizzle (r5-validated): 576 blocks = 8 XCDs x 72
  const int vblk = (blockIdx.x & 7)*72 + (blockIdx.x >> 3);
  const int item = vblk*256 + tid;
  const int yx = item % kHW; const int bh = item / kHW;
  const int b = bh >> 3, head = bh & 7;
  const int x = yx % 96, y = yx / 96;
  const float* vp = vf32 + (size_t)(b*8 + head)*kM;   // nearest-n image, f32

  // ---- correlation argmax (f64, all 5 taps' loads hoisted via clamped addresses) ----
  float off_[8], attn_[4];
  {
    float qv[16];
    { const float4* q4 = (const float4*)(qb + (size_t)bh*kM + yx*16);
      #pragma unroll
      for (int g = 0; g < 4; ++g){ float4 t = q4[g]; qv[g*4]=t.x; qv[g*4+1]=t.y; qv[g*4+2]=t.z; qv[g*4+3]=t.w; } }
    const int sdx[5] = {0,-1,1,0,0};   // SHIFTS entries are (dx,dy)
    const int sdy[5] = {0,0,0,-1,1};
    float4 tv[5][4]; bool valid[5];
    #pragma unroll
    for (int s5 = 0; s5 < 5; ++s5) {
      int sy = y - sdy[s5], sx = x - sdx[s5];
      valid[s5] = (sy >= 0 && sy < 96 && sx >= 0 && sx < 96);
      int syc = min(max(sy,0),95), sxc = min(max(sx,0),95);
      const float4* tp = (const float4*)(vp + (syc*96+sxc)*16);
      tv[s5][0] = tp[0]; tv[s5][1] = tp[1]; tv[s5][2] = tp[2]; tv[s5][3] = tp[3];
    }
    double bsc = 0.0; int best = 0;
    #pragma unroll
    for (int s5 = 0; s5 < 5; ++s5) {
      double sc = 0.0;
      if (valid[s5]) {
        const float* tp = (const float*)&tv[s5][0];
        #pragma unroll
        for (int hd = 0; hd < 16; ++hd) sc += (double)qv[hd]*(double)tp[hd];
      }
      if (s5 == 0) { bsc = sc; best = 0; }
      else if (sc > bsc) { bsc = sc; best = s5; }
    }
    const float STEP = 2.0f/96.0f;
    float ox = 0.f, oy = 0.f;        // reference swap: x-offset = dy*2/W, y-offset = dx*2/H
    if (best == 3) ox = -STEP; else if (best == 4) ox = STEP;
    if (best == 1) oy = -STEP; else if (best == 2) oy = STEP;
    #pragma unroll
    for (int p = 0; p < 4; ++p) { off_[2*p] = ox; off_[2*p+1] = oy; attn_[p] = 0.0f; }
  }

  float h[16];
  { const float4* n4 = (const float4*)(netb + (size_t)item*16);
    #pragma unroll
    for (int g = 0; g < 4; ++g){ float4 t = n4[g]; h[g*4]=t.x; h[g*4+1]=t.y; h[g*4+2]=t.z; h[g*4+3]=t.w; } }

  __syncthreads();   // LDS weights ready

  // ---- 3 GRU refinement iterations, all state in registers (f32 sampling) ----
  for (int it = 0; it < 3; ++it) {
    const float p0x = off_[0];
    const float p0y = off_[1];
    Bilin bl = make_bilin(x, y, p0x, p0y);
    float xv[20];
    sample16(vp, bl, xv);
    xv[16] = p0x; xv[17] = p0y; xv[18] = 0.f; xv[19] = 0.f;

    float hn[16];
    #pragma unroll 2
    for (int j = 0; j < 16; ++j) {
      float g0 = s_bih[j], g1 = s_bih[16+j], g2 = s_bih[32+j];
      const float4* w0r = (const float4*)&s_wih[j*20];
      const float4* w1r = (const float4*)&s_wih[(16+j)*20];
      const float4* w2r = (const float4*)&s_wih[(32+j)*20];
      #pragma unroll
      for (int q4 = 0; q4 < 5; ++q4) {
        float4 w0 = w0r[q4], w1 = w1r[q4], w2 = w2r[q4];
        float a0 = xv[q4*4+0], a1 = xv[q4*4+1], a2 = xv[q4*4+2], a3 = xv[q4*4+3];
        g0 = fmaf(a0,w0.x,g0); g0 = fmaf(a1,w0.y,g0); g0 = fmaf(a2,w0.z,g0); g0 = fmaf(a3,w0.w,g0);
        g1 = fmaf(a0,w1.x,g1); g1 = fmaf(a1,w1.y,g1); g1 = fmaf(a2,w1.z,g1); g1 = fmaf(a3,w1.w,g1);
        g2 = fmaf(a0,w2.x,g2); g2 = fmaf(a1,w2.y,g2); g2 = fmaf(a2,w2.z,g2); g2 = fmaf(a3,w2.w,g2);
      }
      float t0 = s_bhh[j], t1 = s_bhh[16+j], t2 = s_bhh[32+j];
      const float4* h0r = (const float4*)&s_whh[j*16];
      const float4* h1r = (const float4*)&s_whh[(16+j)*16];
      const float4* h2r = (const float4*)&s_whh[(32+j)*16];
      #pragma unroll
      for (int q4 = 0; q4 < 4; ++q4) {
        float4 w0 = h0r[q4], w1 = h1r[q4], w2 = h2r[q4];
        float a0 = h[q4*4+0], a1 = h[q4*4+1], a2 = h[q4*4+2], a3 = h[q4*4+3];
        t0 = fmaf(a0,w0.x,t0); t0 = fmaf(a1,w0.y,t0); t0 = fmaf(a2,w0.z,t0); t0 = fmaf(a3,w0.w,t0);
        t1 = fmaf(a0,w1.x,t1); t1 = fmaf(a1,w1.y,t1); t1 = fmaf(a2,w1.z,t1); t1 = fmaf(a3,w1.w,t1);
        t2 = fmaf(a0,w2.x,t2); t2 = fmaf(a1,w2.y,t2); t2 = fmaf(a2,w2.z,t2); t2 = fmaf(a3,w2.w,t2);
      }
      float r = sigm_f(g0 + t0);
      float z = sigm_f(g1 + t1);
      float nn = tanhf(fmaf(r, t2, g2));
      hn[j] = fmaf(z, h[j], (1.0f - z)*nn);
    }
    #pragma unroll
    for (int j = 0; j < 16; ++j) h[j] = hn[j];

    #pragma unroll
    for (int d = 0; d < 8; ++d) {
      const float4* wr = (const float4*)&s_offw[d*16];
      float s = s_offb[d];
      #pragma unroll
      for (int q4 = 0; q4 < 4; ++q4) {
        float4 w4 = wr[q4];
        s = fmaf(h[q4*4+0], w4.x, s); s = fmaf(h[q4*4+1], w4.y, s);
        s = fmaf(h[q4*4+2], w4.z, s); s = fmaf(h[q4*4+3], w4.w, s);
      }
      off_[d] += s;
    }
    #pragma unroll
    for (int p = 0; p < 4; ++p) {
      const float4* wr = (const float4*)&s_aw[p*16];
      float s = s_ab[p];
      #pragma unroll
      for (int q4 = 0; q4 < 4; ++q4) {
        float4 w4 = wr[q4];
        s = fmaf(h[q4*4+0], w4.x, s); s = fmaf(h[q4*4+1], w4.y, s);
        s = fmaf(h[q4*4+2], w4.z, s); s = fmaf(h[q4*4+3], w4.w, s);
      }
      attn_[p] += s;
    }
  }

  // ---- softmax over (N,P) + entropy ----
  float lg[16];
  #pragma unroll
  for (int n = 0; n < 4; ++n) {
    float tv2 = tbb[(b*8+head)*4 + n];
    #pragma unroll
    for (int p = 0; p < 4; ++p) lg[n*4+p] = attn_[p] + tv2;
  }
  float mx = lg[0];
  #pragma unroll
  for (int i = 1; i < 16; ++i) mx = fmaxf(mx, lg[i]);
  float es = 0.f;
  #pragma unroll
  for (int i = 0; i < 16; ++i){ lg[i] = expf(lg[i]-mx); es += lg[i]; }
  float inv = 1.0f/es;
  float ent = 0.f;
  #pragma unroll
  for (int i = 0; i < 16; ++i){ lg[i] *= inv; ent -= lg[i]*logf(lg[i] + 1e-8f); }
  entb[item] = ent;

  // ---- N*P deformable sampling (bf16 v), p-outer n-inner, loads batched per p ----
  float acc[16];
  #pragma unroll
  for (int j = 0; j < 16; ++j) acc[j] = 0.f;
  #pragma unroll
  for (int p = 0; p < 4; ++p) {
    Bilin bl = make_bilin(x, y, off_[2*p], off_[2*p+1]);
    uint4 raw[4][8];
    #pragma unroll
    for (int n = 0; n < 4; ++n) {
      const u16* vpn = vb16 + (size_t)((b*4+n)*8 + head)*kM;
      raw[n][0] = *(const uint4*)(vpn + bl.i00); raw[n][1] = *(const uint4*)(vpn + bl.i00 + 8);
      raw[n][2] = *(const uint4*)(vpn + bl.i10); raw[n][3] = *(const uint4*)(vpn + bl.i10 + 8);
      raw[n][4] = *(const uint4*)(vpn + bl.i01); raw[n][5] = *(const uint4*)(vpn + bl.i01 + 8);
      raw[n][6] = *(const uint4*)(vpn + bl.i11); raw[n][7] = *(const uint4*)(vpn + bl.i11 + 8);
    }
    #pragma unroll
    for (int n = 0; n < 4; ++n) {
      u32 aw2[8] = {raw[n][0].x,raw[n][0].y,raw[n][0].z,raw[n][0].w, raw[n][1].x,raw[n][1].y,raw[n][1].z,raw[n][1].w};
      u32 bw2[8] = {raw[n][2].x,raw[n][2].y,raw[n][2].z,raw[n][2].w, raw[n][3].x,raw[n][3].y,raw[n][3].z,raw[n][3].w};
      u32 cw2[8] = {raw[n][4].x,raw[n][4].y,raw[n][4].z,raw[n][4].w, raw[n][5].x,raw[n][5].y,raw[n][5].z,raw[n][5].w};
      u32 dw2[8] = {raw[n][6].x,raw[n][6].y,raw[n][6].z,raw[n][6].w, raw[n][7].x,raw[n][7].y,raw[n][7].z,raw[n][7].w};
      float wnp = lg[n*4+p];
      #pragma unroll
      for (int g = 0; g < 8; ++g){
        float alo = __uint_as_float(aw2[g]<<16), ahi = __uint_as_float(aw2[g]&0xffff0000u);
        float blo = __uint_as_float(bw2[g]<<16), bhi = __uint_as_float(bw2[g]&0xffff0000u);
        float clo = __uint_as_float(cw2[g]<<16), chi = __uint_as_float(cw2[g]&0xffff0000u);
        float dlo = __uint_as_float(dw2[g]<<16), dhi = __uint_as_float(dw2[g]&0xffff0000u);
        float s0 = alo*bl.w00 + blo*bl.w10 + clo*bl.w01 + dlo*bl.w11;
        float s1 = ahi*bl.w00 + bhi*bl.w10 + chi*bl.w01 + dhi*bl.w11;
        acc[g*2+0] = fmaf(wnp, s0, acc[g*2+0]);
        acc[g*2+1] = fmaf(wnp, s1, acc[g*2+1]);
      }
    }
  }
  uint4 pk0, pk1;
  pk0.x = (u32)f2bf(acc[0])  | ((u32)f2bf(acc[1])<<16);
  pk0.y = (u32)f2bf(acc[2])  | ((u32)f2bf(acc[3])<<16);
  pk0.z = (u32)f2bf(acc[4])  | ((u32)f2bf(acc[5])<<16);
  pk0.w = (u32)f2bf(acc[6])  | ((u32)f2bf(acc[7])<<16);
  pk1.x = (u32)f2bf(acc[8])  | ((u32)f2bf(acc[9])<<16);
  pk1.y = (u32)f2bf(acc[10]) | ((u32)f2bf(acc[11])<<16);
  pk1.z = (u32)f2bf(acc[12]) | ((u32)f2bf(acc[13])<<16);
  pk1.w = (u32)f2bf(acc[14]) | ((u32)f2bf(acc[15])<<16);
  *(uint4*)(outattn16 + (size_t)item*16)     = pk0;
  *(uint4*)(outattn16 + (size_t)item*16 + 8) = pk1;
}

// ---------------- TAIL: o1o2 (y=0,1) + entropy reduction (y=2) in one launch --------------
__global__ __launch_bounds__(256) void tail_k(const u16* __restrict__ oat,
    const float* __restrict__ wt1, const float* __restrict__ o1b,
    const float* __restrict__ wt2, const float* __restrict__ o2b,
    const float* __restrict__ gate, const float* __restrict__ entb, float* __restrict__ out)
{
  __shared__ __align__(16) float a_s[16*68];
  __shared__ __align__(16) float b_s[16*132];
  __shared__ __align__(16) float mid[128*68];   // 34.8 KB
  const int tid = threadIdx.x;
  if (blockIdx.y == 2) {
    // entropy mean over heads -> confidence/entropy outputs (f32)
    if (blockIdx.x >= 72) return;
    int idx = blockIdx.x*256 + tid;   // B*HW = 18432
    int b = idx / kHW, yx = idx % kHW;
    float s = 0.f;
    #pragma unroll
    for (int h8 = 0; h8 < 8; ++h8) s += entb[(b*8+h8)*kHW + yx];
    s *= 0.125f;
    float conf = 1.0f - fminf(fmaxf(s / (2.772588722239781f + 1e-8f), 0.0f), 1.0f);
    out[2359296 + idx]         = conf;
    out[2359296 + 18432 + idx] = s;
    return;
  }
  const int tx = tid & 15, ty = tid >> 4;       // tx: 8-out group, ty: 4-px group
  const int img = blockIdx.y;
  const int px0 = blockIdx.x * 64;
  const int sr = tid >> 4;
  const int sc = (tid & 15) * 8;

  float acc[32];                                 // [pi(4)][oj(8)]
  // ---- stage 1: o1 GEMM (bf16 item-major input), bias-first k-ascending ----
  #pragma unroll
  for (int oj = 0; oj < 8; ++oj) {
    float bv = o1b[tx*8+oj];
    #pragma unroll
    for (int pi = 0; pi < 4; ++pi) acc[pi*8+oj] = bv;
  }
  for (int kc = 0; kc < 8; ++kc) {
    const int k0 = kc*16;
    { const float4* g = (const float4*)(wt1 + (k0+sr)*128 + sc);
      float4 v0 = g[0], v1 = g[1];
      *(float4*)&b_s[sr*132+sc] = v0; *(float4*)&b_s[sr*132+sc+4] = v1; }
    { const int px = tid & 63, hd0 = (tid >> 6) * 4;
      uint2 raw = *(const uint2*)(oat + ((size_t)(img*8 + kc)*kHW + px0 + px)*16 + hd0);
      a_s[(hd0+0)*68+px] = __uint_as_float(raw.x<<16);
      a_s[(hd0+1)*68+px] = __uint_as_float(raw.x&0xffff0000u);
      a_s[(hd0+2)*68+px] = __uint_as_float(raw.y<<16);
      a_s[(hd0+3)*68+px] = __uint_as_float(raw.y&0xffff0000u); }
    __syncthreads();
    #pragma unroll
    for (int k = 0; k < 16; ++k) {
      float4 b0 = *(const float4*)&b_s[k*132 + tx*8];
      float4 b1 = *(const float4*)&b_s[k*132 + tx*8 + 4];
      float4 a0 = *(const float4*)&a_s[k*68 + ty*4];
      float av[4] = {a0.x,a0.y,a0.z,a0.w};
      float bv[8] = {b0.x,b0.y,b0.z,b0.w,b1.x,b1.y,b1.z,b1.w};
      #pragma unroll
      for (int pi = 0; pi < 4; ++pi)
        #pragma unroll
        for (int oj = 0; oj < 8; ++oj)
          acc[pi*8+oj] = fmaf(av[pi], bv[oj], acc[pi*8+oj]);
    }
    __syncthreads();
  }
  // gelu -> mid (planar [ch][px_local])
  #pragma unroll
  for (int oj = 0; oj < 8; ++oj)
    #pragma unroll
    for (int pi = 0; pi < 4; ++pi)
      mid[(tx*8+oj)*68 + ty*4+pi] = gelu_f(acc[pi*8+oj]);
  __syncthreads();

  // ---- stage 2: o2 GEMM, A read directly from LDS mid ----
  #pragma unroll
  for (int oj = 0; oj < 8; ++oj) {
    float bv = o2b[tx*8+oj];
    #pragma unroll
    for (int pi = 0; pi < 4; ++pi) acc[pi*8+oj] = bv;
  }
  for (int kc = 0; kc < 8; ++kc) {
    const int k0 = kc*16;
    { const float4* g = (const float4*)(wt2 + (k0+sr)*128 + sc);
      float4 v0 = g[0], v1 = g[1];
      *(float4*)&b_s[sr*132+sc] = v0; *(float4*)&b_s[sr*132+sc+4] = v1; }
    __syncthreads();
    #pragma unroll
    for (int k = 0; k < 16; ++k) {
      float4 b0 = *(const float4*)&b_s[k*132 + tx*8];
      float4 b1 = *(const float4*)&b_s[k*132 + tx*8 + 4];
      float4 a0 = *(const float4*)&mid[(k0+k)*68 + ty*4];
      float av[4] = {a0.x,a0.y,a0.z,a0.w};
      float bv[8] = {b0.x,b0.y,b0.z,b0.w,b1.x,b1.y,b1.z,b1.w};
      #pragma unroll
      for (int pi = 0; pi < 4; ++pi)
        #pragma unroll
        for (int oj = 0; oj < 8; ++oj)
          acc[pi*8+oj] = fmaf(av[pi], bv[oj], acc[pi*8+oj]);
    }
    __syncthreads();
  }
  #pragma unroll
  for (int oj = 0; oj < 8; ++oj) {
    const int o = tx*8 + oj;
    float* dst = out + (size_t)(img*128 + o)*kHW + px0 + ty*4;
    float sg = sigm_f(gate[o]);
    float4 t0 = {acc[0*8+oj]*sg, acc[1*8+oj]*sg, acc[2*8+oj]*sg, acc[3*8+oj]*sg};
    *(float4*)dst = t0;
  }
}

extern "C" void kernel_launch(void* const* d_in, const int* in_sizes, int n_in,
                              void* d_out, int out_size, void* d_ws, size_t ws_size,
                              hipStream_t stream)
{
  const float* query  = (const float*)d_in[0];
  const float* values = (const float*)d_in[1];
  const float* relt   = (const float*)d_in[2];
  const float* time_enc = (const float*)d_in[3];
  const float* qw  = (const float*)d_in[4];
  const float* qb  = (const float*)d_in[5];
  const float* vw  = (const float*)d_in[6];
  const float* vb  = (const float*)d_in[7];
  const float* dww = (const float*)d_in[8];
  const float* dwb = (const float*)d_in[9];
  const float* pww = (const float*)d_in[10];
  const float* pwb = (const float*)d_in[11];
  const float* wih = (const float*)d_in[12];
  const float* whh = (const float*)d_in[13];
  const float* bih = (const float*)d_in[14];
  const float* bhh = (const float*)d_in[15];
  const float* offw = (const float*)d_in[16];
  const float* offb = (const float*)d_in[17];
  const float* aw  = (const float*)d_in[18];
  const float* ab  = (const float*)d_in[19];
  const float* tw  = (const float*)d_in[20];
  const float* tb  = (const float*)d_in[21];
  const float* o1w = (const float*)d_in[22];
  const float* o1b = (const float*)d_in[23];
  const float* o2w = (const float*)d_in[24];
  const float* o2b = (const float*)d_in[25];
  const float* gate = (const float*)d_in[26];
  float* out = (float*)d_out;
  float* ws = (float*)d_ws;

  // workspace layout (f32 slots) — total 14385280 slots = 57.5 MB
  u16*   vb16   = (u16*)ws;                        // bf16 v, item-major [(b,n,h)][yx][16] : 4718592 fl
  float* vf32n  = ws + 4718592;                    // f32 v of nearest n [(b,h)][yx][16]   : 2359296
  float* qbuf   = ws + 7077888;                    // q item-major [(b,h)][yx][16]          : 2359296
  float* netb   = ws + 9437184;                    // net item-major [bh][yx][16]           : 2359296
  float* dwbuf  = ws + 11796480;                   // dw mid planar [b][c][yx]              : 2359296 ; reused as outattn16
  u16*   oat16  = (u16*)dwbuf;                     // outattn bf16 [item][16]               : 2359296 u16
  float* entbf  = ws + 14155776;                   // per-head entropy                      :  147456
  float* tbbuf  = ws + 14303232;                   // time bias                             :      64
  float* wtbuf  = ws + 14303360;                   // 5 transposed weights                  :   81920
  if (ws_size < 14385280ull * 4ull) return;

  float* wt_o1 = wtbuf + 49152;
  float* wt_o2 = wtbuf + 65536;

  dim3 blk(256,1,1);
  // 1. PRE: dw conv + weight transpose + time bias (independent jobs, one launch)
  pre_k<<<dim3(9537,1,1), blk, 0, stream>>>(query, dww, dwb, dwbuf,
                                            qw, vw, pww, o1w, o2w, wtbuf,
                                            time_enc, tw, tb, tbbuf);
  // 2. MEGA-GEMM: q + v + pw in one launch (864 blocks)
  gemm_qvp_k<<<dim3(72,12,1), blk, 0, stream>>>(query, values, dwbuf, wtbuf,
                                                qb, vb, pwb, qbuf, netb, vf32n, vb16, relt);
  // 3. FUSED (r10 structure) -> oat16 (overwrites dwbuf, its consumers are done)
  fused_k<<<dim3(576,1,1), blk, 0, stream>>>(qbuf, vf32n, vb16, netb, relt,
                                             wih, whh, bih, bhh, offw, offb, aw, ab,
                                             tbbuf, oat16, entbf);
  // 4. TAIL: fused o1(gelu)->o2(gate) + entropy/confidence outputs
  tail_k<<<dim3(144,3,1), blk, 0, stream>>>(oat16, wt_o1, o1b, wt_o2, o2b, gate, entbf, out);
}